// Round 1
// baseline (883.380 us; speedup 1.0000x reference)
//
#include <hip/hip_runtime.h>
#include <math.h>

#define BETA 0.9f
#define THR 1.0f

constexpr int B_ = 64, T_ = 256, F_ = 1024, H_ = 512;
constexpr int M_ = B_ * T_;  // 16384 rows

// ---------------------------------------------------------------------------
// GEMM NT: C[i,j] = sum_k A[i,k] * Bm[j,k] + bias[j], optional relu.
// A: [M,K] row-major, Bm: [N,K] row-major (i.e. C = A @ Bm^T + bias).
// BM=128, BN=64, BK=16, 256 threads, 8x4 register microtile per thread.
// ---------------------------------------------------------------------------
__global__ __launch_bounds__(256) void gemm_nt(const float* __restrict__ A,
                                               const float* __restrict__ Bm,
                                               const float* __restrict__ bias,
                                               float* __restrict__ C,
                                               int M, int N, int K, int relu) {
    __shared__ float As[128 * 20];  // row stride 20 (pad) keeps float4 aligned
    __shared__ float Bs[64 * 20];

    const int tid = threadIdx.x;
    const int n0 = blockIdx.x * 64;
    const int m0 = blockIdx.y * 128;
    const int tx = tid & 15;   // N direction
    const int ty = tid >> 4;   // M direction (0..15)
    const int lr = tid >> 2;   // staging row 0..63
    const int lk = (tid & 3) * 4;  // staging k-offset 0,4,8,12

    float acc[8][4];
#pragma unroll
    for (int mi = 0; mi < 8; ++mi)
#pragma unroll
        for (int ni = 0; ni < 4; ++ni) acc[mi][ni] = 0.f;

    for (int k0 = 0; k0 < K; k0 += 16) {
        float4 a0 = *(const float4*)&A[(size_t)(m0 + lr) * K + k0 + lk];
        float4 a1 = *(const float4*)&A[(size_t)(m0 + lr + 64) * K + k0 + lk];
        float4 b0 = *(const float4*)&Bm[(size_t)(n0 + lr) * K + k0 + lk];
        __syncthreads();  // previous iteration's reads done
        *(float4*)&As[lr * 20 + lk] = a0;
        *(float4*)&As[(lr + 64) * 20 + lk] = a1;
        *(float4*)&Bs[lr * 20 + lk] = b0;
        __syncthreads();

#pragma unroll
        for (int kk = 0; kk < 4; ++kk) {
            float4 av[8], bv[4];
#pragma unroll
            for (int mi = 0; mi < 8; ++mi)
                av[mi] = *(const float4*)&As[(ty + 16 * mi) * 20 + kk * 4];
#pragma unroll
            for (int ni = 0; ni < 4; ++ni)
                bv[ni] = *(const float4*)&Bs[(tx + 16 * ni) * 20 + kk * 4];
#pragma unroll
            for (int mi = 0; mi < 8; ++mi)
#pragma unroll
                for (int ni = 0; ni < 4; ++ni) {
                    acc[mi][ni] += av[mi].x * bv[ni].x;
                    acc[mi][ni] += av[mi].y * bv[ni].y;
                    acc[mi][ni] += av[mi].z * bv[ni].z;
                    acc[mi][ni] += av[mi].w * bv[ni].w;
                }
        }
    }

#pragma unroll
    for (int ni = 0; ni < 4; ++ni) {
        const int col = n0 + tx + 16 * ni;
        const float bvl = bias ? bias[col] : 0.f;
#pragma unroll
        for (int mi = 0; mi < 8; ++mi) {
            const int row = m0 + ty + 16 * mi;
            float v = acc[mi][ni] + bvl;
            if (relu) v = fmaxf(v, 0.f);
            C[(size_t)row * N + col] = v;
        }
    }
}

// ---------------------------------------------------------------------------
// snntorch Leaky (subtract reset) elementwise scan over T.
// One thread per (b,h) chain; x: [B,T,H] drive, s: [B,T,H] output spikes.
//   r = spike(m_prev - THR); m = BETA*m_prev + x_t - r*THR; s_t = spike(m - THR)
// ---------------------------------------------------------------------------
__global__ __launch_bounds__(256) void leaky_scan(const float* x, float* s) {
    const int idx = blockIdx.x * 256 + threadIdx.x;  // 0 .. B*H-1
    const int b = idx >> 9;          // /H_
    const int h = idx & (H_ - 1);    // %H_
    const float* xp = x + (size_t)b * T_ * H_ + h;
    float* sp = s + (size_t)b * T_ * H_ + h;
    float m = 0.f;
#pragma unroll 4
    for (int t = 0; t < T_; ++t) {
        const float xv = xp[(size_t)t * H_];
        const float r = (m - THR > 0.f) ? THR : 0.f;
        m = BETA * m + xv - r;
        sp[(size_t)t * H_] = (m - THR > 0.f) ? 1.f : 0.f;
    }
}

// ---------------------------------------------------------------------------
// Fused MIL layer 2 + 3 + sigmoid. One wave per row.
// z: [M,512] (already relu'd); z2[j] = z@Mw2[j,:]+Mb2[j] (j<32);
// logit = sigmoid(z2 . Mw3 + Mb3).
// ---------------------------------------------------------------------------
__global__ __launch_bounds__(256) void mil23(const float* __restrict__ z,
                                             const float* __restrict__ Mw2,
                                             const float* __restrict__ Mb2,
                                             const float* __restrict__ Mw3,
                                             const float* __restrict__ Mb3,
                                             float* __restrict__ logits, int M) {
    const int row = (blockIdx.x * 256 + threadIdx.x) >> 6;
    const int lane = threadIdx.x & 63;
    if (row >= M) return;
    const int j = lane & 31;
    const int half = lane >> 5;  // 0 or 1: split K=512 into two 256 halves
    const float* zh = z + (size_t)row * 512 + half * 256;
    const float* wr = Mw2 + (size_t)j * 512 + half * 256;
    float acc = 0.f;
    for (int k = 0; k < 256; ++k) acc += zh[k] * wr[k];
    acc += __shfl_xor(acc, 32);           // combine halves -> z2 partial
    float v = (acc + Mb2[j]) * Mw3[j];    // weighted by Mw3
    v += __shfl_xor(v, 16);
    v += __shfl_xor(v, 8);
    v += __shfl_xor(v, 4);
    v += __shfl_xor(v, 2);
    v += __shfl_xor(v, 1);
    if (lane == 0) {
        const float lg = v + Mb3[0];
        logits[row] = 1.f / (1.f + expf(-lg));
    }
}

// ---------------------------------------------------------------------------
// Top-17 mean per batch row (T=256 logits each). One wave per row, 4
// values/lane, 17 iterations of wave argmax + remove.
// ---------------------------------------------------------------------------
__global__ __launch_bounds__(64) void topk_mean(const float* __restrict__ logits,
                                                float* __restrict__ out) {
    const int b = blockIdx.x;
    const int lane = threadIdx.x;
    float v[4];
#pragma unroll
    for (int i = 0; i < 4; ++i) v[i] = logits[b * T_ + lane + i * 64];
    float sum = 0.f;
    for (int iter = 0; iter < 17; ++iter) {
        float mv = v[0];
        int mslot = 0;
#pragma unroll
        for (int i = 1; i < 4; ++i)
            if (v[i] > mv) { mv = v[i]; mslot = i; }
        float bv = mv;
        int bl = lane, bs = mslot;
#pragma unroll
        for (int off = 32; off >= 1; off >>= 1) {
            const float ov = __shfl_xor(bv, off);
            const int ol = __shfl_xor(bl, off);
            const int os = __shfl_xor(bs, off);
            if (ov > bv || (ov == bv && ol < bl)) { bv = ov; bl = ol; bs = os; }
        }
        sum += bv;
        if (lane == bl) v[bs] = -1e30f;  // remove one instance
    }
    if (lane == 0) out[b] = sum * (1.f / 17.f);
}

// ---------------------------------------------------------------------------
// Orchestration. Workspace schedule (no aliasing at any step):
//   buf0 <- h = gemm(f_f, Wf, bf)            [33.5 MB]
//   buf1 <- x1 = gemm(buf0, W1, b1)          [33.5 MB]
//   buf0 <- s1 = scan(buf1)                  (h dead)
//   buf1 <- x2 = gemm(buf0, W2, b2)          (x1 dead)
//   buf0 <- spk = scan(buf1)                 (s1 dead)
//   buf1 <- z = gemm(buf0, Mw1, Mb1, relu)   (x2 dead)
//   logits <- mil23(buf1)
//   out <- topk_mean(logits)
// ---------------------------------------------------------------------------
extern "C" void kernel_launch(void* const* d_in, const int* in_sizes, int n_in,
                              void* d_out, int out_size, void* d_ws, size_t ws_size,
                              hipStream_t stream) {
    const float* f_f = (const float*)d_in[0];
    // d_in[1] = seq_len (int64), unused: all == T, k = T/16+1 is static.
    const float* Wf  = (const float*)d_in[2];
    const float* bf  = (const float*)d_in[3];
    const float* W1  = (const float*)d_in[4];
    const float* b1  = (const float*)d_in[5];
    const float* W2  = (const float*)d_in[6];
    const float* b2  = (const float*)d_in[7];
    const float* Mw1 = (const float*)d_in[8];
    const float* Mb1 = (const float*)d_in[9];
    const float* Mw2 = (const float*)d_in[10];
    const float* Mb2 = (const float*)d_in[11];
    const float* Mw3 = (const float*)d_in[12];
    const float* Mb3 = (const float*)d_in[13];
    float* out = (float*)d_out;

    char* ws = (char*)d_ws;
    const size_t bufBytes = (size_t)M_ * H_ * sizeof(float);  // 33.5 MB
    float* buf0 = (float*)ws;
    float* buf1 = (float*)(ws + bufBytes);
    float* logits = (float*)(ws + 2 * bufBytes);

    const dim3 blk(256);
    const dim3 g1(H_ / 64, M_ / 128);  // (8, 128)

    gemm_nt<<<g1, blk, 0, stream>>>(f_f, Wf, bf, buf0, M_, H_, F_, 0);
    gemm_nt<<<g1, blk, 0, stream>>>(buf0, W1, b1, buf1, M_, H_, H_, 0);
    leaky_scan<<<dim3((B_ * H_) / 256), blk, 0, stream>>>(buf1, buf0);
    gemm_nt<<<g1, blk, 0, stream>>>(buf0, W2, b2, buf1, M_, H_, H_, 0);
    leaky_scan<<<dim3((B_ * H_) / 256), blk, 0, stream>>>(buf1, buf0);
    gemm_nt<<<g1, blk, 0, stream>>>(buf0, Mw1, Mb1, buf1, M_, H_, H_, 1);
    mil23<<<dim3(M_ / 4), blk, 0, stream>>>(buf1, Mw2, Mb2, Mw3, Mb3, logits, M_);
    topk_mean<<<dim3(B_), dim3(64), 0, stream>>>(logits, out);
}

// Round 2
// 347.986 us; speedup vs baseline: 2.5386x; 2.5386x over previous
//
#include <hip/hip_runtime.h>
#include <math.h>

#define BETA 0.9f
#define THR 1.0f

constexpr int B_ = 64, T_ = 256, F_ = 1024, H_ = 512;
constexpr int M_ = B_ * T_;  // 16384 rows

typedef float f32x4 __attribute__((ext_vector_type(4)));
typedef short short8 __attribute__((ext_vector_type(8)));
typedef unsigned short ushort8 __attribute__((ext_vector_type(8)));
typedef unsigned short us4 __attribute__((ext_vector_type(4)));
typedef unsigned short ushort_t;

// ---- bf16 helpers (RNE) ----------------------------------------------------
static __device__ __forceinline__ unsigned short f2bf(float x) {
    unsigned b = __builtin_bit_cast(unsigned, x);
    unsigned r = (b + 0x7FFFu + ((b >> 16) & 1u)) >> 16;
    return (unsigned short)r;
}
static __device__ __forceinline__ float bf2f(unsigned short u) {
    unsigned v = ((unsigned)u) << 16;
    return __builtin_bit_cast(float, v);
}
// XOR swizzle: mixes 4 row bits into the 16B-chunk index -> conflict-free
// ds_read_b128 at 64B row stride (G4; st_16x32 family).
static __device__ __forceinline__ int swz(int r) {
    return ((r >> 2) & 3) ^ (r & 3);
}

#define GLDS(srcp, dstp)                                                      \
    __builtin_amdgcn_global_load_lds(                                         \
        (const __attribute__((address_space(1))) unsigned int*)(srcp),        \
        (__attribute__((address_space(3))) unsigned int*)(dstp), 16, 0, 0)

// ---------------------------------------------------------------------------
// Split-bf16 MFMA GEMM: C[i,j] = sum_k A[i,k]*Bw[j,k] + bias[j]  (A @ Bw^T)
// ASPLIT=1: A is f32, reg-staged with on-the-fly hi/lo split, 3 MFMA products.
// ASPLIT=0: A is bf16 (exact spikes), 2 MFMA products (weight split only).
// Tile 128x128, BK=32, 256 threads = 4 waves (2x2), 16x16x32 bf16 MFMA.
// ---------------------------------------------------------------------------
template <int ASPLIT, int RELU>
__global__ __launch_bounds__(256) void gemm_mfma(
    const void* __restrict__ Asrc, const ushort_t* __restrict__ Bhi,
    const ushort_t* __restrict__ Blo, const float* __restrict__ bias,
    float* __restrict__ C, int M, int N, int K) {
    __shared__ ushort_t lds[16384];  // 32 KB: AHI | ALO | BHI | BLO (4x8KB)
    constexpr int AHI = 0, ALO = 4096, BHI = 8192, BLO = 12288;

    const int tid = threadIdx.x;
    const int w = tid >> 6, l = tid & 63;
    const int n0 = blockIdx.x * 128, m0 = blockIdx.y * 128;
    const int wr = w >> 1, wc = w & 1;  // wave -> 64x64 sub-tile

    f32x4 acc[4][4];
#pragma unroll
    for (int mi = 0; mi < 4; ++mi)
#pragma unroll
        for (int ni = 0; ni < 4; ++ni) acc[mi][ni] = (f32x4){0.f, 0.f, 0.f, 0.f};

    for (int k0 = 0; k0 < K; k0 += 32) {
        __syncthreads();  // prior iteration's ds_reads done before overwrite

        // ---- B staging via global_load_lds, source pre-swizzled (m173) ----
        // 2 tiles x 8 segments of 1KB; 4 loads per wave.
        {
            const int rB = (l >> 2);
            const int cB = (l & 3);
#pragma unroll
            for (int j = 0; j < 4; ++j) {
                const int g = w * 4 + j;  // 0..15
                const int seg = g & 7;
                const int r = seg * 16 + rB;
                const int cs = cB ^ swz(r);
                const ushort_t* wsrc = (g < 8 ? Bhi : Blo);
                const ushort_t* src = wsrc + (size_t)(n0 + r) * K + k0 + cs * 8;
                ushort_t* dst = &lds[(g < 8 ? BHI : BLO) + seg * 512];
                GLDS(src, dst);
            }
        }

        // ---- A staging ----
        if (ASPLIT) {
            // f32 source -> hi/lo bf16, swizzled ds_write_b128
#pragma unroll
            for (int q = 0; q < 2; ++q) {
                const int g = q * 256 + tid;  // 0..511 chunks (16B bf16 each)
                const int r = g >> 2, c = g & 3;
                const float* src =
                    (const float*)Asrc + (size_t)(m0 + r) * K + k0 + c * 8;
                f32x4 v0 = *(const f32x4*)src;
                f32x4 v1 = *(const f32x4*)(src + 4);
                ushort8 hi, lo;
#pragma unroll
                for (int e = 0; e < 4; ++e) {
                    unsigned short h0 = f2bf(v0[e]);
                    unsigned short h1 = f2bf(v1[e]);
                    hi[e] = h0;
                    hi[e + 4] = h1;
                    lo[e] = f2bf(v0[e] - bf2f(h0));
                    lo[e + 4] = f2bf(v1[e] - bf2f(h1));
                }
                const int off = r * 32 + ((c ^ swz(r)) * 8);
                *(ushort8*)&lds[AHI + off] = hi;
                *(ushort8*)&lds[ALO + off] = lo;
            }
        } else {
            // bf16 source (spikes), swizzled copy
#pragma unroll
            for (int q = 0; q < 2; ++q) {
                const int g = q * 256 + tid;
                const int r = g >> 2, c = g & 3;
                const ushort_t* src =
                    (const ushort_t*)Asrc + (size_t)(m0 + r) * K + k0 + c * 8;
                ushort8 v = *(const ushort8*)src;
                *(ushort8*)&lds[AHI + r * 32 + ((c ^ swz(r)) * 8)] = v;
            }
        }

        __syncthreads();  // drains vmcnt (global_load_lds) + lgkm (ds_write)

        // ---- fragments ----
        short8 ah[4], al[4], bh[4], bl[4];
        const int c0 = l >> 4;
#pragma unroll
        for (int mi = 0; mi < 4; ++mi) {
            const int r = wr * 64 + mi * 16 + (l & 15);
            const int off = r * 32 + ((c0 ^ swz(r)) * 8);
            ah[mi] = *(const short8*)&lds[AHI + off];
            if (ASPLIT) al[mi] = *(const short8*)&lds[ALO + off];
        }
#pragma unroll
        for (int ni = 0; ni < 4; ++ni) {
            const int r = wc * 64 + ni * 16 + (l & 15);
            const int off = r * 32 + ((c0 ^ swz(r)) * 8);
            bh[ni] = *(const short8*)&lds[BHI + off];
            bl[ni] = *(const short8*)&lds[BLO + off];
        }

        // ---- MFMA: hihi + hilo (+ lohi) ----
#pragma unroll
        for (int mi = 0; mi < 4; ++mi)
#pragma unroll
            for (int ni = 0; ni < 4; ++ni) {
                acc[mi][ni] = __builtin_amdgcn_mfma_f32_16x16x32_bf16(
                    ah[mi], bh[ni], acc[mi][ni], 0, 0, 0);
                acc[mi][ni] = __builtin_amdgcn_mfma_f32_16x16x32_bf16(
                    ah[mi], bl[ni], acc[mi][ni], 0, 0, 0);
                if (ASPLIT)
                    acc[mi][ni] = __builtin_amdgcn_mfma_f32_16x16x32_bf16(
                        al[mi], bh[ni], acc[mi][ni], 0, 0, 0);
            }
    }

    // ---- epilogue: C/D layout col=lane&15, row=(lane>>4)*4+reg (m89) ----
#pragma unroll
    for (int ni = 0; ni < 4; ++ni) {
        const int col = n0 + wc * 64 + ni * 16 + (l & 15);
        const float bv = bias[col];
#pragma unroll
        for (int mi = 0; mi < 4; ++mi) {
            const int row0 = m0 + wr * 64 + mi * 16 + ((l >> 4) << 2);
#pragma unroll
            for (int r = 0; r < 4; ++r) {
                float v = acc[mi][ni][r] + bv;
                if (RELU) v = fmaxf(v, 0.f);
                C[(size_t)(row0 + r) * N + col] = v;
            }
        }
    }
}

// ---------------------------------------------------------------------------
// Weight hi/lo split: w (f32, n4*4 elems) -> hi, lo bf16 arrays.
// ---------------------------------------------------------------------------
__global__ __launch_bounds__(256) void split_w(const float* __restrict__ w,
                                               ushort_t* __restrict__ hi,
                                               ushort_t* __restrict__ lo) {
    const int i = blockIdx.x * 256 + threadIdx.x;
    f32x4 v = ((const f32x4*)w)[i];
    us4 h, ll;
#pragma unroll
    for (int e = 0; e < 4; ++e) {
        unsigned short hb = f2bf(v[e]);
        h[e] = hb;
        ll[e] = f2bf(v[e] - bf2f(hb));
    }
    ((us4*)hi)[i] = h;
    ((us4*)lo)[i] = ll;
}

// ---------------------------------------------------------------------------
// snntorch Leaky (subtract reset) scan; x f32 [B,T,H] -> spikes bf16 [B,T,H].
// ---------------------------------------------------------------------------
__global__ __launch_bounds__(256) void leaky_scan(const float* __restrict__ x,
                                                  ushort_t* __restrict__ s) {
    const int idx = blockIdx.x * 256 + threadIdx.x;  // 0 .. B*H-1
    const int b = idx >> 9;
    const int h = idx & (H_ - 1);
    const float* xp = x + (size_t)b * T_ * H_ + h;
    ushort_t* sp = s + (size_t)b * T_ * H_ + h;
    float m = 0.f;
#pragma unroll 8
    for (int t = 0; t < T_; ++t) {
        const float xv = xp[(size_t)t * H_];
        const float r = (m - THR > 0.f) ? THR : 0.f;
        m = BETA * m + xv - r;
        sp[(size_t)t * H_] = (m - THR > 0.f) ? (ushort_t)0x3F80 : (ushort_t)0;
    }
}

// ---------------------------------------------------------------------------
// Fused MIL layer 2 + 3 + sigmoid. One wave per row.
// ---------------------------------------------------------------------------
__global__ __launch_bounds__(256) void mil23(const float* __restrict__ z,
                                             const float* __restrict__ Mw2,
                                             const float* __restrict__ Mb2,
                                             const float* __restrict__ Mw3,
                                             const float* __restrict__ Mb3,
                                             float* __restrict__ logits, int M) {
    const int row = (blockIdx.x * 256 + threadIdx.x) >> 6;
    const int lane = threadIdx.x & 63;
    if (row >= M) return;
    const int j = lane & 31;
    const int half = lane >> 5;
    const float* zh = z + (size_t)row * 512 + half * 256;
    const float* wr = Mw2 + (size_t)j * 512 + half * 256;
    float acc = 0.f;
    for (int k = 0; k < 256; ++k) acc += zh[k] * wr[k];
    acc += __shfl_xor(acc, 32);
    float v = (acc + Mb2[j]) * Mw3[j];
    v += __shfl_xor(v, 16);
    v += __shfl_xor(v, 8);
    v += __shfl_xor(v, 4);
    v += __shfl_xor(v, 2);
    v += __shfl_xor(v, 1);
    if (lane == 0) {
        logits[row] = 1.f / (1.f + expf(-(v + Mb3[0])));
    }
}

// ---------------------------------------------------------------------------
// Top-17 mean per batch row. One wave per row.
// ---------------------------------------------------------------------------
__global__ __launch_bounds__(64) void topk_mean(const float* __restrict__ logits,
                                                float* __restrict__ out) {
    const int b = blockIdx.x;
    const int lane = threadIdx.x;
    float v[4];
#pragma unroll
    for (int i = 0; i < 4; ++i) v[i] = logits[b * T_ + lane + i * 64];
    float sum = 0.f;
    for (int iter = 0; iter < 17; ++iter) {
        float mv = v[0];
        int mslot = 0;
#pragma unroll
        for (int i = 1; i < 4; ++i)
            if (v[i] > mv) { mv = v[i]; mslot = i; }
        float bv = mv;
        int bl = lane, bs = mslot;
#pragma unroll
        for (int off = 32; off >= 1; off >>= 1) {
            const float ov = __shfl_xor(bv, off);
            const int ol = __shfl_xor(bl, off);
            const int os = __shfl_xor(bs, off);
            if (ov > bv || (ov == bv && ol < bl)) { bv = ov; bl = ol; bs = os; }
        }
        sum += bv;
        if (lane == bl) v[bs] = -1e30f;
    }
    if (lane == 0) out[b] = sum * (1.f / 17.f);
}

// ---------------------------------------------------------------------------
// Orchestration.
//   h_f32 <- gemm1(f_f, Wf)         x_f32 <- gemm2(h, W1)
//   s_bf16 <- scan(x_f32)           h_f32 <- gemm3(s_bf16, W2)   (h dead)
//   s_bf16 <- scan(h_f32)           x_f32 <- gemm4(s_bf16, Mw1)  (x1 dead)
//   logits <- mil23(x_f32)          out <- topk(logits)
// ---------------------------------------------------------------------------
extern "C" void kernel_launch(void* const* d_in, const int* in_sizes, int n_in,
                              void* d_out, int out_size, void* d_ws, size_t ws_size,
                              hipStream_t stream) {
    const float* f_f = (const float*)d_in[0];
    const float* Wf  = (const float*)d_in[2];
    const float* bf  = (const float*)d_in[3];
    const float* W1  = (const float*)d_in[4];
    const float* b1  = (const float*)d_in[5];
    const float* W2  = (const float*)d_in[6];
    const float* b2  = (const float*)d_in[7];
    const float* Mw1 = (const float*)d_in[8];
    const float* Mb1 = (const float*)d_in[9];
    const float* Mw2 = (const float*)d_in[10];
    const float* Mb2 = (const float*)d_in[11];
    const float* Mw3 = (const float*)d_in[12];
    const float* Mb3 = (const float*)d_in[13];
    float* out = (float*)d_out;

    char* ws = (char*)d_ws;
    const size_t MB32 = (size_t)M_ * H_;  // elems per activation matrix
    float* h_f32 = (float*)ws;                                 // 33.5 MB
    float* x_f32 = (float*)(ws + MB32 * 4);                    // 33.5 MB
    ushort_t* s_bf = (ushort_t*)(ws + MB32 * 8);               // 16.8 MB
    char* wp = ws + MB32 * 10;
    ushort_t* wfh = (ushort_t*)wp;                 // 512*1024
    ushort_t* wfl = wfh + 524288;
    ushort_t* w1h = wfl + 524288;                  // 512*512 each below
    ushort_t* w1l = w1h + 262144;
    ushort_t* w2h = w1l + 262144;
    ushort_t* w2l = w2h + 262144;
    ushort_t* m1h = w2l + 262144;
    ushort_t* m1l = m1h + 262144;
    float* logits = (float*)(m1l + 262144 + 128);

    const dim3 blk(256);
    const dim3 gg(H_ / 128, M_ / 128);  // (4, 128)

    split_w<<<dim3(524288 / 1024), blk, 0, stream>>>(Wf, wfh, wfl);
    split_w<<<dim3(262144 / 1024), blk, 0, stream>>>(W1, w1h, w1l);
    split_w<<<dim3(262144 / 1024), blk, 0, stream>>>(W2, w2h, w2l);
    split_w<<<dim3(262144 / 1024), blk, 0, stream>>>(Mw1, m1h, m1l);

    gemm_mfma<1, 0><<<gg, blk, 0, stream>>>(f_f, wfh, wfl, bf, h_f32, M_, H_, F_);
    gemm_mfma<1, 0><<<gg, blk, 0, stream>>>(h_f32, w1h, w1l, b1, x_f32, M_, H_, H_);
    leaky_scan<<<dim3((B_ * H_) / 256), blk, 0, stream>>>(x_f32, s_bf);
    gemm_mfma<0, 0><<<gg, blk, 0, stream>>>(s_bf, w2h, w2l, b2, h_f32, M_, H_, H_);
    leaky_scan<<<dim3((B_ * H_) / 256), blk, 0, stream>>>(h_f32, s_bf);
    gemm_mfma<0, 1><<<gg, blk, 0, stream>>>(s_bf, m1h, m1l, Mb1, x_f32, M_, H_, H_);
    mil23<<<dim3(M_ / 4), blk, 0, stream>>>(x_f32, Mw2, Mb2, Mw3, Mb3, logits, M_);
    topk_mean<<<dim3(B_), dim3(64), 0, stream>>>(logits, out);
}

// Round 3
// 238.173 us; speedup vs baseline: 3.7090x; 1.4611x over previous
//
#include <hip/hip_runtime.h>
#include <math.h>

#define BETA 0.9f
#define THR 1.0f

constexpr int B_ = 64, T_ = 256, F_ = 1024, H_ = 512;
constexpr int M_ = B_ * T_;  // 16384 rows

typedef float f32x4 __attribute__((ext_vector_type(4)));
typedef short short8 __attribute__((ext_vector_type(8)));
typedef unsigned short ushort8 __attribute__((ext_vector_type(8)));
typedef unsigned short us4 __attribute__((ext_vector_type(4)));
typedef unsigned short ushort_t;

// ---- bf16 helpers (RNE) ----------------------------------------------------
static __device__ __forceinline__ unsigned short f2bf(float x) {
    unsigned b = __builtin_bit_cast(unsigned, x);
    unsigned r = (b + 0x7FFFu + ((b >> 16) & 1u)) >> 16;
    return (unsigned short)r;
}
static __device__ __forceinline__ float bf2f(unsigned short u) {
    unsigned v = ((unsigned)u) << 16;
    return __builtin_bit_cast(float, v);
}
// XOR swizzle: mixes row bits into the 16B-chunk index -> conflict-free
// ds_read_b128 at 64B row stride (G4; st_16x32 family).
static __device__ __forceinline__ int swz(int r) {
    return ((r >> 2) & 3) ^ (r & 3);
}

#define GLDS(srcp, dstp)                                                      \
    __builtin_amdgcn_global_load_lds(                                         \
        (const __attribute__((address_space(1))) unsigned int*)(srcp),        \
        (__attribute__((address_space(3))) unsigned int*)(dstp), 16, 0, 0)

// ---------------------------------------------------------------------------
// Split-bf16 MFMA GEMM: C[i,j] = sum_k A[i,k]*Bw[j,k] + bias[j]  (A @ Bw^T)
// ASPLIT=1: A is f32, reg-staged with on-the-fly hi/lo split, 3 MFMA products.
// ASPLIT=0: A is bf16 (exact spikes), 2 MFMA products (weight split only).
// Tile 128x128, BK=32, 256 threads = 4 waves (2x2), 16x16x32 bf16 MFMA.
// ---------------------------------------------------------------------------
template <int ASPLIT, int RELU>
__global__ __launch_bounds__(256) void gemm_mfma(
    const void* __restrict__ Asrc, const ushort_t* __restrict__ Bhi,
    const ushort_t* __restrict__ Blo, const float* __restrict__ bias,
    float* __restrict__ C, int M, int N, int K) {
    __shared__ ushort_t lds[16384];  // 32 KB: AHI | ALO | BHI | BLO (4x8KB)
    constexpr int AHI = 0, ALO = 4096, BHI = 8192, BLO = 12288;

    const int tid = threadIdx.x;
    const int w = tid >> 6, l = tid & 63;
    const int n0 = blockIdx.x * 128, m0 = blockIdx.y * 128;
    const int wr = w >> 1, wc = w & 1;  // wave -> 64x64 sub-tile

    f32x4 acc[4][4];
#pragma unroll
    for (int mi = 0; mi < 4; ++mi)
#pragma unroll
        for (int ni = 0; ni < 4; ++ni) acc[mi][ni] = (f32x4){0.f, 0.f, 0.f, 0.f};

    for (int k0 = 0; k0 < K; k0 += 32) {
        __syncthreads();  // prior iteration's ds_reads done before overwrite

        // ---- B staging via global_load_lds, source pre-swizzled (m173) ----
        {
            const int rB = (l >> 2);
            const int cB = (l & 3);
#pragma unroll
            for (int j = 0; j < 4; ++j) {
                const int g = w * 4 + j;  // 0..15
                const int seg = g & 7;
                const int r = seg * 16 + rB;
                const int cs = cB ^ swz(r);
                const ushort_t* wsrc = (g < 8 ? Bhi : Blo);
                const ushort_t* src = wsrc + (size_t)(n0 + r) * K + k0 + cs * 8;
                ushort_t* dst = &lds[(g < 8 ? BHI : BLO) + seg * 512];
                GLDS(src, dst);
            }
        }

        // ---- A staging ----
        if (ASPLIT) {
#pragma unroll
            for (int q = 0; q < 2; ++q) {
                const int g = q * 256 + tid;  // 0..511 chunks (16B bf16 each)
                const int r = g >> 2, c = g & 3;
                const float* src =
                    (const float*)Asrc + (size_t)(m0 + r) * K + k0 + c * 8;
                f32x4 v0 = *(const f32x4*)src;
                f32x4 v1 = *(const f32x4*)(src + 4);
                ushort8 hi, lo;
#pragma unroll
                for (int e = 0; e < 4; ++e) {
                    unsigned short h0 = f2bf(v0[e]);
                    unsigned short h1 = f2bf(v1[e]);
                    hi[e] = h0;
                    hi[e + 4] = h1;
                    lo[e] = f2bf(v0[e] - bf2f(h0));
                    lo[e + 4] = f2bf(v1[e] - bf2f(h1));
                }
                const int off = r * 32 + ((c ^ swz(r)) * 8);
                *(ushort8*)&lds[AHI + off] = hi;
                *(ushort8*)&lds[ALO + off] = lo;
            }
        } else {
#pragma unroll
            for (int q = 0; q < 2; ++q) {
                const int g = q * 256 + tid;
                const int r = g >> 2, c = g & 3;
                const ushort_t* src =
                    (const ushort_t*)Asrc + (size_t)(m0 + r) * K + k0 + c * 8;
                ushort8 v = *(const ushort8*)src;
                *(ushort8*)&lds[AHI + r * 32 + ((c ^ swz(r)) * 8)] = v;
            }
        }

        __syncthreads();  // drains vmcnt (global_load_lds) + lgkm (ds_write)

        // ---- fragments ----
        short8 ah[4], al[4], bh[4], bl[4];
        const int c0 = l >> 4;
#pragma unroll
        for (int mi = 0; mi < 4; ++mi) {
            const int r = wr * 64 + mi * 16 + (l & 15);
            const int off = r * 32 + ((c0 ^ swz(r)) * 8);
            ah[mi] = *(const short8*)&lds[AHI + off];
            if (ASPLIT) al[mi] = *(const short8*)&lds[ALO + off];
        }
#pragma unroll
        for (int ni = 0; ni < 4; ++ni) {
            const int r = wc * 64 + ni * 16 + (l & 15);
            const int off = r * 32 + ((c0 ^ swz(r)) * 8);
            bh[ni] = *(const short8*)&lds[BHI + off];
            bl[ni] = *(const short8*)&lds[BLO + off];
        }

        // ---- MFMA: hihi + hilo (+ lohi) ----
#pragma unroll
        for (int mi = 0; mi < 4; ++mi)
#pragma unroll
            for (int ni = 0; ni < 4; ++ni) {
                acc[mi][ni] = __builtin_amdgcn_mfma_f32_16x16x32_bf16(
                    ah[mi], bh[ni], acc[mi][ni], 0, 0, 0);
                acc[mi][ni] = __builtin_amdgcn_mfma_f32_16x16x32_bf16(
                    ah[mi], bl[ni], acc[mi][ni], 0, 0, 0);
                if (ASPLIT)
                    acc[mi][ni] = __builtin_amdgcn_mfma_f32_16x16x32_bf16(
                        al[mi], bh[ni], acc[mi][ni], 0, 0, 0);
            }
    }

    // ---- epilogue: C/D layout col=lane&15, row=(lane>>4)*4+reg (m89) ----
#pragma unroll
    for (int ni = 0; ni < 4; ++ni) {
        const int col = n0 + wc * 64 + ni * 16 + (l & 15);
        const float bv = bias[col];
#pragma unroll
        for (int mi = 0; mi < 4; ++mi) {
            const int row0 = m0 + wr * 64 + mi * 16 + ((l >> 4) << 2);
#pragma unroll
            for (int r = 0; r < 4; ++r) {
                float v = acc[mi][ni][r] + bv;
                if (RELU) v = fmaxf(v, 0.f);
                C[(size_t)(row0 + r) * N + col] = v;
            }
        }
    }
}

// ---------------------------------------------------------------------------
// mil2+mil3+sigmoid fused, MFMA. z [M,512] f32 @ Mw2^T [512,32] -> z2 [M,32];
// logit = sigmoid(sum_j (z2[r,j]+Mb2[j])*Mw3[j] + Mb3). One block = 128 rows,
// 4 waves x 32 rows. A staged hi/lo in LDS (verified ASPLIT path); B (64KB)
// read per-fragment from global (L2-resident). N=32, K=512.
// ---------------------------------------------------------------------------
__global__ __launch_bounds__(256) void mil2_mfma(
    const float* __restrict__ z, const ushort_t* __restrict__ Bhi,
    const ushort_t* __restrict__ Blo, const float* __restrict__ Mb2,
    const float* __restrict__ Mw3, const float* __restrict__ Mb3,
    float* __restrict__ logits) {
    __shared__ ushort_t lds[8192];  // AHI | ALO (8KB each)
    constexpr int AHI = 0, ALO = 4096;
    constexpr int K = 512;

    const int tid = threadIdx.x;
    const int w = tid >> 6, l = tid & 63;
    const int m0 = blockIdx.x * 128;

    f32x4 acc[2][2];
#pragma unroll
    for (int mi = 0; mi < 2; ++mi)
#pragma unroll
        for (int ni = 0; ni < 2; ++ni) acc[mi][ni] = (f32x4){0.f, 0.f, 0.f, 0.f};

    const int c0 = l >> 4;
    for (int k0 = 0; k0 < K; k0 += 32) {
        __syncthreads();
        // A staging: f32 -> hi/lo bf16, swizzled (same as gemm_mfma ASPLIT)
#pragma unroll
        for (int q = 0; q < 2; ++q) {
            const int g = q * 256 + tid;
            const int r = g >> 2, c = g & 3;
            const float* src = z + (size_t)(m0 + r) * K + k0 + c * 8;
            f32x4 v0 = *(const f32x4*)src;
            f32x4 v1 = *(const f32x4*)(src + 4);
            ushort8 hi, lo;
#pragma unroll
            for (int e = 0; e < 4; ++e) {
                unsigned short h0 = f2bf(v0[e]);
                unsigned short h1 = f2bf(v1[e]);
                hi[e] = h0;
                hi[e + 4] = h1;
                lo[e] = f2bf(v0[e] - bf2f(h0));
                lo[e + 4] = f2bf(v1[e] - bf2f(h1));
            }
            const int off = r * 32 + ((c ^ swz(r)) * 8);
            *(ushort8*)&lds[AHI + off] = hi;
            *(ushort8*)&lds[ALO + off] = lo;
        }
        __syncthreads();

        short8 ah[2], al[2], bh[2], bl[2];
#pragma unroll
        for (int mi = 0; mi < 2; ++mi) {
            const int r = w * 32 + mi * 16 + (l & 15);
            const int off = r * 32 + ((c0 ^ swz(r)) * 8);
            ah[mi] = *(const short8*)&lds[AHI + off];
            al[mi] = *(const short8*)&lds[ALO + off];
        }
#pragma unroll
        for (int ni = 0; ni < 2; ++ni) {
            const size_t boff = (size_t)(ni * 16 + (l & 15)) * K + k0 + c0 * 8;
            bh[ni] = *(const short8*)&Bhi[boff];
            bl[ni] = *(const short8*)&Blo[boff];
        }
#pragma unroll
        for (int mi = 0; mi < 2; ++mi)
#pragma unroll
            for (int ni = 0; ni < 2; ++ni) {
                acc[mi][ni] = __builtin_amdgcn_mfma_f32_16x16x32_bf16(
                    ah[mi], bh[ni], acc[mi][ni], 0, 0, 0);
                acc[mi][ni] = __builtin_amdgcn_mfma_f32_16x16x32_bf16(
                    ah[mi], bl[ni], acc[mi][ni], 0, 0, 0);
                acc[mi][ni] = __builtin_amdgcn_mfma_f32_16x16x32_bf16(
                    al[mi], bh[ni], acc[mi][ni], 0, 0, 0);
            }
    }

    // Epilogue: per-lane weighted col-sum, 16-lane row-reduce, sigmoid.
    float mw3v[2], mb2v[2];
#pragma unroll
    for (int ni = 0; ni < 2; ++ni) {
        const int j = ni * 16 + (l & 15);
        mw3v[ni] = Mw3[j];
        mb2v[ni] = Mb2[j];
    }
    const float b3 = Mb3[0];
#pragma unroll
    for (int mi = 0; mi < 2; ++mi) {
        float p[4];
#pragma unroll
        for (int r = 0; r < 4; ++r) {
            float s = 0.f;
#pragma unroll
            for (int ni = 0; ni < 2; ++ni)
                s += (acc[mi][ni][r] + mb2v[ni]) * mw3v[ni];
            p[r] = s;
        }
#pragma unroll
        for (int off = 1; off <= 8; off <<= 1)
#pragma unroll
            for (int r = 0; r < 4; ++r) p[r] += __shfl_xor(p[r], off);
        if ((l & 15) == 0) {
#pragma unroll
            for (int r = 0; r < 4; ++r) {
                const int row = m0 + w * 32 + mi * 16 + ((l >> 4) << 2) + r;
                logits[row] = 1.f / (1.f + expf(-(p[r] + b3)));
            }
        }
    }
}

// ---------------------------------------------------------------------------
// Weight hi/lo split: w (f32, n4*4 elems) -> hi, lo bf16 arrays.
// ---------------------------------------------------------------------------
__global__ __launch_bounds__(256) void split_w(const float* __restrict__ w,
                                               ushort_t* __restrict__ hi,
                                               ushort_t* __restrict__ lo) {
    const int i = blockIdx.x * 256 + threadIdx.x;
    f32x4 v = ((const f32x4*)w)[i];
    us4 h, ll;
#pragma unroll
    for (int e = 0; e < 4; ++e) {
        unsigned short hb = f2bf(v[e]);
        h[e] = hb;
        ll[e] = f2bf(v[e] - bf2f(hb));
    }
    ((us4*)hi)[i] = h;
    ((us4*)lo)[i] = ll;
}

// ---------------------------------------------------------------------------
// snntorch Leaky (subtract reset) scan; x f32 [B,T,H] -> spikes bf16 [B,T,H].
// ---------------------------------------------------------------------------
__global__ __launch_bounds__(256) void leaky_scan(const float* __restrict__ x,
                                                  ushort_t* __restrict__ s) {
    const int idx = blockIdx.x * 256 + threadIdx.x;  // 0 .. B*H-1
    const int b = idx >> 9;
    const int h = idx & (H_ - 1);
    const float* xp = x + (size_t)b * T_ * H_ + h;
    ushort_t* sp = s + (size_t)b * T_ * H_ + h;
    float m = 0.f;
#pragma unroll 8
    for (int t = 0; t < T_; ++t) {
        const float xv = xp[(size_t)t * H_];
        const float r = (m - THR > 0.f) ? THR : 0.f;
        m = BETA * m + xv - r;
        sp[(size_t)t * H_] = (m - THR > 0.f) ? (ushort_t)0x3F80 : (ushort_t)0;
    }
}

// ---------------------------------------------------------------------------
// Top-17 mean per batch row. One wave per row.
// ---------------------------------------------------------------------------
__global__ __launch_bounds__(64) void topk_mean(const float* __restrict__ logits,
                                                float* __restrict__ out) {
    const int b = blockIdx.x;
    const int lane = threadIdx.x;
    float v[4];
#pragma unroll
    for (int i = 0; i < 4; ++i) v[i] = logits[b * T_ + lane + i * 64];
    float sum = 0.f;
    for (int iter = 0; iter < 17; ++iter) {
        float mv = v[0];
        int mslot = 0;
#pragma unroll
        for (int i = 1; i < 4; ++i)
            if (v[i] > mv) { mv = v[i]; mslot = i; }
        float bv = mv;
        int bl = lane, bs = mslot;
#pragma unroll
        for (int off = 32; off >= 1; off >>= 1) {
            const float ov = __shfl_xor(bv, off);
            const int ol = __shfl_xor(bl, off);
            const int os = __shfl_xor(bs, off);
            if (ov > bv || (ov == bv && ol < bl)) { bv = ov; bl = ol; bs = os; }
        }
        sum += bv;
        if (lane == bl) v[bs] = -1e30f;
    }
    if (lane == 0) out[b] = sum * (1.f / 17.f);
}

// ---------------------------------------------------------------------------
// Orchestration.
//   h_f32 <- gemm1(f_f, Wf)         x_f32 <- gemm2(h, W1)
//   s_bf16 <- scan(x_f32)           h_f32 <- gemm3(s_bf16, W2)   (h dead)
//   s_bf16 <- scan(h_f32)           x_f32 <- gemm4(s_bf16, Mw1)  (x1 dead)
//   logits <- mil2_mfma(x_f32)      out <- topk(logits)
// ---------------------------------------------------------------------------
extern "C" void kernel_launch(void* const* d_in, const int* in_sizes, int n_in,
                              void* d_out, int out_size, void* d_ws, size_t ws_size,
                              hipStream_t stream) {
    const float* f_f = (const float*)d_in[0];
    const float* Wf  = (const float*)d_in[2];
    const float* bf  = (const float*)d_in[3];
    const float* W1  = (const float*)d_in[4];
    const float* b1  = (const float*)d_in[5];
    const float* W2  = (const float*)d_in[6];
    const float* b2  = (const float*)d_in[7];
    const float* Mw1 = (const float*)d_in[8];
    const float* Mb1 = (const float*)d_in[9];
    const float* Mw2 = (const float*)d_in[10];
    const float* Mb2 = (const float*)d_in[11];
    const float* Mw3 = (const float*)d_in[12];
    const float* Mb3 = (const float*)d_in[13];
    float* out = (float*)d_out;

    char* ws = (char*)d_ws;
    const size_t MB32 = (size_t)M_ * H_;  // elems per activation matrix
    float* h_f32 = (float*)ws;                                 // 33.5 MB
    float* x_f32 = (float*)(ws + MB32 * 4);                    // 33.5 MB
    ushort_t* s_bf = (ushort_t*)(ws + MB32 * 8);               // 16.8 MB
    char* wp = ws + MB32 * 10;
    ushort_t* wfh = (ushort_t*)wp;                 // 512*1024
    ushort_t* wfl = wfh + 524288;
    ushort_t* w1h = wfl + 524288;                  // 512*512 each below
    ushort_t* w1l = w1h + 262144;
    ushort_t* w2h = w1l + 262144;
    ushort_t* w2l = w2h + 262144;
    ushort_t* m1h = w2l + 262144;
    ushort_t* m1l = m1h + 262144;
    ushort_t* m2h = m1l + 262144;                  // 32*512
    ushort_t* m2l = m2h + 16384;
    float* logits = (float*)(m2l + 16384 + 128);

    const dim3 blk(256);
    const dim3 gg(H_ / 128, M_ / 128);  // (4, 128)

    split_w<<<dim3(524288 / 1024), blk, 0, stream>>>(Wf, wfh, wfl);
    split_w<<<dim3(262144 / 1024), blk, 0, stream>>>(W1, w1h, w1l);
    split_w<<<dim3(262144 / 1024), blk, 0, stream>>>(W2, w2h, w2l);
    split_w<<<dim3(262144 / 1024), blk, 0, stream>>>(Mw1, m1h, m1l);
    split_w<<<dim3(16384 / 1024), blk, 0, stream>>>(Mw2, m2h, m2l);

    gemm_mfma<1, 0><<<gg, blk, 0, stream>>>(f_f, wfh, wfl, bf, h_f32, M_, H_, F_);
    gemm_mfma<1, 0><<<gg, blk, 0, stream>>>(h_f32, w1h, w1l, b1, x_f32, M_, H_, H_);
    leaky_scan<<<dim3((B_ * H_) / 256), blk, 0, stream>>>(x_f32, s_bf);
    gemm_mfma<0, 0><<<gg, blk, 0, stream>>>(s_bf, w2h, w2l, b2, h_f32, M_, H_, H_);
    leaky_scan<<<dim3((B_ * H_) / 256), blk, 0, stream>>>(h_f32, s_bf);
    gemm_mfma<0, 1><<<gg, blk, 0, stream>>>(s_bf, m1h, m1l, Mb1, x_f32, M_, H_, H_);
    mil2_mfma<<<dim3(M_ / 128), blk, 0, stream>>>(x_f32, m2h, m2l, Mb2, Mw3, Mb3,
                                                  logits);
    topk_mean<<<dim3(B_), dim3(64), 0, stream>>>(logits, out);
}

// Round 4
// 223.490 us; speedup vs baseline: 3.9527x; 1.0657x over previous
//
#include <hip/hip_runtime.h>
#include <math.h>

#define BETA 0.9f
#define THR 1.0f

constexpr int B_ = 64, T_ = 256, F_ = 1024, H_ = 512;
constexpr int M_ = B_ * T_;  // 16384 rows

typedef float f32x4 __attribute__((ext_vector_type(4)));
typedef short short8 __attribute__((ext_vector_type(8)));
typedef unsigned short ushort8 __attribute__((ext_vector_type(8)));
typedef unsigned short us4 __attribute__((ext_vector_type(4)));
typedef unsigned short ushort_t;

// ---- bf16 helpers (RNE) ----------------------------------------------------
static __device__ __forceinline__ unsigned short f2bf(float x) {
    unsigned b = __builtin_bit_cast(unsigned, x);
    unsigned r = (b + 0x7FFFu + ((b >> 16) & 1u)) >> 16;
    return (unsigned short)r;
}
static __device__ __forceinline__ float bf2f(unsigned short u) {
    unsigned v = ((unsigned)u) << 16;
    return __builtin_bit_cast(float, v);
}
// XOR swizzle on 16B chunks within a 64B row; involution, applied on both
// the global source address (GLDS path / ds_write) and the ds_read (rule #21).
static __device__ __forceinline__ int swz(int r) {
    return ((r >> 2) & 3) ^ (r & 3);
}

#define GLDS(srcp, dstp)                                                      \
    __builtin_amdgcn_global_load_lds(                                         \
        (const __attribute__((address_space(1))) unsigned int*)(srcp),        \
        (__attribute__((address_space(3))) unsigned int*)(dstp), 16, 0, 0)

// ---------------------------------------------------------------------------
// Split-bf16 MFMA GEMM, depth-1 single-barrier pipeline (T3 minimum 2-phase).
// C = A @ Bw^T + bias. Tile 128x128, BK=32, 4 waves (2x2), 16x16x32 MFMA.
// AMODE 0: A = single bf16 plane (exact spikes), 2 products.
// AMODE 1: A = bf16 hi/lo planes (GLDS), 3 products.
// AMODE 2: A = f32, reg-load early + convert/ds_write late (T14), 3 products.
// OUTMODE 0: f32 C. OUTMODE 1: hi/lo bf16 planes.
// Grid fixed (4,128) = 512 wg; XCD-bijective swizzle (q=64).
// ---------------------------------------------------------------------------
template <int AMODE, int RELU, int OUTMODE>
__global__ __launch_bounds__(256) void gemm_dp(
    const float* __restrict__ Af, const ushort_t* __restrict__ Ah,
    const ushort_t* __restrict__ Al, const ushort_t* __restrict__ Bh,
    const ushort_t* __restrict__ Bl, const float* __restrict__ bias,
    float* __restrict__ Cf, ushort_t* __restrict__ Ch,
    ushort_t* __restrict__ Cl, int M, int N, int K) {
    constexpr int APL = (AMODE == 0) ? 1 : 2;
    constexpr int BUFSZ = (APL + 2) * 4096;  // ushorts per buffer
    __shared__ ushort_t lds[2 * BUFSZ];

    const int tid = threadIdx.x;
    const int w = tid >> 6, l = tid & 63;
    // XCD swizzle: flat -> wg, 8 XCDs x 64 contiguous wgs (nwg=512, 8|512)
    const int flat = blockIdx.y * 4 + blockIdx.x;
    const int wg = (flat & 7) * 64 + (flat >> 3);
    const int n0 = (wg & 3) * 128, m0 = (wg >> 2) * 128;
    const int wr = w >> 1, wc = w & 1;

    f32x4 acc[4][4];
#pragma unroll
    for (int mi = 0; mi < 4; ++mi)
#pragma unroll
        for (int ni = 0; ni < 4; ++ni) acc[mi][ni] = (f32x4){0.f, 0.f, 0.f, 0.f};

    f32x4 areg[4];  // AMODE2: staged A f32 for next tile

    auto loadA = [&](int k0) {  // AMODE2 only: issue global f32 loads early
#pragma unroll
        for (int j = 0; j < 4; ++j) {
            const int g = w * 4 + j;           // 0..15
            const int r = g * 8 + (l >> 3);    // 0..127
            const int c = (l & 7) * 4;
            areg[j] = *(const f32x4*)&Af[(size_t)(m0 + r) * K + k0 + c];
        }
    };
    auto writeA = [&](int buf) {  // AMODE2 only: convert + swizzled ds_write
#pragma unroll
        for (int j = 0; j < 4; ++j) {
            const int g = w * 4 + j;
            const int r = g * 8 + (l >> 3);
            const int c = (l & 7) * 4;
            us4 hi, lo;
#pragma unroll
            for (int e = 0; e < 4; ++e) {
                const unsigned short h = f2bf(areg[j][e]);
                hi[e] = h;
                lo[e] = f2bf(areg[j][e] - bf2f(h));
            }
            const int off = r * 32 + (((c >> 3) ^ swz(r)) * 8) + (c & 7);
            *(us4*)&lds[buf + off] = hi;
            *(us4*)&lds[buf + 4096 + off] = lo;
        }
    };
    auto stage = [&](int buf, int k0) {  // GLDS staging, pre-swizzled source
        if constexpr (AMODE != 2) {
#pragma unroll
            for (int j = 0; j < APL * 2; ++j) {
                const int g = w * (APL * 2) + j;  // 0 .. APL*8-1
                const int p = g >> 3, seg = g & 7;
                const int r = seg * 16 + (l >> 2);
                const int ch = (l & 3) ^ swz(r);
                const ushort_t* src =
                    (p ? Al : Ah) + (size_t)(m0 + r) * K + k0 + ch * 8;
                GLDS(src, &lds[buf + p * 4096 + seg * 512]);
            }
        }
#pragma unroll
        for (int j = 0; j < 4; ++j) {
            const int g = w * 4 + j;  // 0..15
            const int p = g >> 3, seg = g & 7;
            const int r = seg * 16 + (l >> 2);
            const int ch = (l & 3) ^ swz(r);
            const ushort_t* src =
                (p ? Bl : Bh) + (size_t)(n0 + r) * K + k0 + ch * 8;
            GLDS(src, &lds[buf + APL * 4096 + p * 4096 + seg * 512]);
        }
    };

    const int nt = K / 32;
    // prologue: fill buffer 0
    if constexpr (AMODE == 2) loadA(0);
    stage(0, 0);
    if constexpr (AMODE == 2) writeA(0);
    __syncthreads();

    const int c0 = l >> 4;
    for (int t = 0; t < nt; ++t) {
        const int cur = (t & 1) * BUFSZ;
        const int nxt = BUFSZ - cur;
        const bool more = (t + 1 < nt);
        if constexpr (AMODE == 2) {
            if (more) loadA((t + 1) * 32);
        }
        if (more) stage(nxt, (t + 1) * 32);

        // fragment reads (current buffer)
        short8 ah[4], al[4], bh[4], bl[4];
#pragma unroll
        for (int mi = 0; mi < 4; ++mi) {
            const int r = wr * 64 + mi * 16 + (l & 15);
            const int off = r * 32 + ((c0 ^ swz(r)) * 8);
            ah[mi] = *(const short8*)&lds[cur + off];
            if constexpr (APL == 2) al[mi] = *(const short8*)&lds[cur + 4096 + off];
        }
#pragma unroll
        for (int ni = 0; ni < 4; ++ni) {
            const int r = wc * 64 + ni * 16 + (l & 15);
            const int off = r * 32 + ((c0 ^ swz(r)) * 8);
            bh[ni] = *(const short8*)&lds[cur + APL * 4096 + off];
            bl[ni] = *(const short8*)&lds[cur + APL * 4096 + 4096 + off];
        }

#pragma unroll
        for (int mi = 0; mi < 4; ++mi)
#pragma unroll
            for (int ni = 0; ni < 4; ++ni) {
                acc[mi][ni] = __builtin_amdgcn_mfma_f32_16x16x32_bf16(
                    ah[mi], bh[ni], acc[mi][ni], 0, 0, 0);
                acc[mi][ni] = __builtin_amdgcn_mfma_f32_16x16x32_bf16(
                    ah[mi], bl[ni], acc[mi][ni], 0, 0, 0);
                if constexpr (APL == 2)
                    acc[mi][ni] = __builtin_amdgcn_mfma_f32_16x16x32_bf16(
                        al[mi], bh[ni], acc[mi][ni], 0, 0, 0);
            }

        if constexpr (AMODE == 2) {
            if (more) writeA(nxt);  // write-late: after MFMA, before barrier
        }
        __syncthreads();
    }

    // epilogue: C/D layout col=lane&15, row=(lane>>4)*4+reg
#pragma unroll
    for (int ni = 0; ni < 4; ++ni) {
        const int col = n0 + wc * 64 + ni * 16 + (l & 15);
        const float bv = bias[col];
#pragma unroll
        for (int mi = 0; mi < 4; ++mi) {
            const int row0 = m0 + wr * 64 + mi * 16 + ((l >> 4) << 2);
#pragma unroll
            for (int r = 0; r < 4; ++r) {
                float v = acc[mi][ni][r] + bv;
                if (RELU) v = fmaxf(v, 0.f);
                const size_t idx = (size_t)(row0 + r) * N + col;
                if constexpr (OUTMODE == 0) {
                    Cf[idx] = v;
                } else {
                    const unsigned short h = f2bf(v);
                    Ch[idx] = h;
                    Cl[idx] = f2bf(v - bf2f(h));
                }
            }
        }
    }
}

// ---------------------------------------------------------------------------
// mil2+mil3+sigmoid fused, MFMA, z from hi/lo planes (pure GLDS staging),
// depth-1 single-barrier. N=32, K=512. One block = 128 rows, 4 waves x 32.
// ---------------------------------------------------------------------------
__global__ __launch_bounds__(256) void mil2_dp(
    const ushort_t* __restrict__ zh, const ushort_t* __restrict__ zl,
    const ushort_t* __restrict__ Bh, const ushort_t* __restrict__ Bl,
    const float* __restrict__ Mb2, const float* __restrict__ Mw3,
    const float* __restrict__ Mb3, float* __restrict__ logits) {
    constexpr int BUFSZ = 2 * 4096;
    __shared__ ushort_t lds[2 * BUFSZ];
    constexpr int K = 512;

    const int tid = threadIdx.x;
    const int w = tid >> 6, l = tid & 63;
    const int m0 = blockIdx.x * 128;

    f32x4 acc[2][2];
#pragma unroll
    for (int mi = 0; mi < 2; ++mi)
#pragma unroll
        for (int ni = 0; ni < 2; ++ni) acc[mi][ni] = (f32x4){0.f, 0.f, 0.f, 0.f};

    auto stageA = [&](int buf, int k0) {
#pragma unroll
        for (int j = 0; j < 4; ++j) {
            const int g = w * 4 + j;  // 0..15
            const int p = g >> 3, seg = g & 7;
            const int r = seg * 16 + (l >> 2);
            const int ch = (l & 3) ^ swz(r);
            const ushort_t* src =
                (p ? zl : zh) + (size_t)(m0 + r) * K + k0 + ch * 8;
            GLDS(src, &lds[buf + p * 4096 + seg * 512]);
        }
    };

    stageA(0, 0);
    __syncthreads();

    const int c0 = l >> 4;
    for (int t = 0; t < 16; ++t) {
        const int cur = (t & 1) * BUFSZ;
        const int nxt = BUFSZ - cur;
        if (t < 15) stageA(nxt, (t + 1) * 32);
        const int k0 = t * 32;

        short8 ah[2], al[2], bh[2], bl[2];
#pragma unroll
        for (int mi = 0; mi < 2; ++mi) {
            const int r = w * 32 + mi * 16 + (l & 15);
            const int off = r * 32 + ((c0 ^ swz(r)) * 8);
            ah[mi] = *(const short8*)&lds[cur + off];
            al[mi] = *(const short8*)&lds[cur + 4096 + off];
        }
#pragma unroll
        for (int ni = 0; ni < 2; ++ni) {
            const size_t boff = (size_t)(ni * 16 + (l & 15)) * K + k0 + c0 * 8;
            bh[ni] = *(const short8*)&Bh[boff];
            bl[ni] = *(const short8*)&Bl[boff];
        }
#pragma unroll
        for (int mi = 0; mi < 2; ++mi)
#pragma unroll
            for (int ni = 0; ni < 2; ++ni) {
                acc[mi][ni] = __builtin_amdgcn_mfma_f32_16x16x32_bf16(
                    ah[mi], bh[ni], acc[mi][ni], 0, 0, 0);
                acc[mi][ni] = __builtin_amdgcn_mfma_f32_16x16x32_bf16(
                    ah[mi], bl[ni], acc[mi][ni], 0, 0, 0);
                acc[mi][ni] = __builtin_amdgcn_mfma_f32_16x16x32_bf16(
                    al[mi], bh[ni], acc[mi][ni], 0, 0, 0);
            }
        __syncthreads();
    }

    // Epilogue: per-lane weighted col-sum, 16-lane row-reduce, sigmoid.
    float mw3v[2], mb2v[2];
#pragma unroll
    for (int ni = 0; ni < 2; ++ni) {
        const int j = ni * 16 + (l & 15);
        mw3v[ni] = Mw3[j];
        mb2v[ni] = Mb2[j];
    }
    const float b3 = Mb3[0];
#pragma unroll
    for (int mi = 0; mi < 2; ++mi) {
        float p[4];
#pragma unroll
        for (int r = 0; r < 4; ++r) {
            float s = 0.f;
#pragma unroll
            for (int ni = 0; ni < 2; ++ni)
                s += (acc[mi][ni][r] + mb2v[ni]) * mw3v[ni];
            p[r] = s;
        }
#pragma unroll
        for (int off = 1; off <= 8; off <<= 1)
#pragma unroll
            for (int r = 0; r < 4; ++r) p[r] += __shfl_xor(p[r], off);
        if ((l & 15) == 0) {
#pragma unroll
            for (int r = 0; r < 4; ++r) {
                const int row = m0 + w * 32 + mi * 16 + ((l >> 4) << 2) + r;
                logits[row] = 1.f / (1.f + expf(-(p[r] + b3)));
            }
        }
    }
}

// ---------------------------------------------------------------------------
// Weight hi/lo split.
// ---------------------------------------------------------------------------
__global__ __launch_bounds__(256) void split_w(const float* __restrict__ w,
                                               ushort_t* __restrict__ hi,
                                               ushort_t* __restrict__ lo) {
    const int i = blockIdx.x * 256 + threadIdx.x;
    f32x4 v = ((const f32x4*)w)[i];
    us4 h, ll;
#pragma unroll
    for (int e = 0; e < 4; ++e) {
        unsigned short hb = f2bf(v[e]);
        h[e] = hb;
        ll[e] = f2bf(v[e] - bf2f(hb));
    }
    ((us4*)hi)[i] = h;
    ((us4*)lo)[i] = ll;
}

// ---------------------------------------------------------------------------
// snntorch Leaky (subtract reset) scan; x f32 [B,T,H] -> spikes bf16.
// ---------------------------------------------------------------------------
__global__ __launch_bounds__(256) void leaky_scan(const float* __restrict__ x,
                                                  ushort_t* __restrict__ s) {
    const int idx = blockIdx.x * 256 + threadIdx.x;
    const int b = idx >> 9;
    const int h = idx & (H_ - 1);
    const float* xp = x + (size_t)b * T_ * H_ + h;
    ushort_t* sp = s + (size_t)b * T_ * H_ + h;
    float m = 0.f;
#pragma unroll 8
    for (int t = 0; t < T_; ++t) {
        const float xv = xp[(size_t)t * H_];
        const float r = (m - THR > 0.f) ? THR : 0.f;
        m = BETA * m + xv - r;
        sp[(size_t)t * H_] = (m - THR > 0.f) ? (ushort_t)0x3F80 : (ushort_t)0;
    }
}

// ---------------------------------------------------------------------------
// Top-17 mean per batch row. One wave per row.
// ---------------------------------------------------------------------------
__global__ __launch_bounds__(64) void topk_mean(const float* __restrict__ logits,
                                                float* __restrict__ out) {
    const int b = blockIdx.x;
    const int lane = threadIdx.x;
    float v[4];
#pragma unroll
    for (int i = 0; i < 4; ++i) v[i] = logits[b * T_ + lane + i * 64];
    float sum = 0.f;
    for (int iter = 0; iter < 17; ++iter) {
        float mv = v[0];
        int mslot = 0;
#pragma unroll
        for (int i = 1; i < 4; ++i)
            if (v[i] > mv) { mv = v[i]; mslot = i; }
        float bv = mv;
        int bl = lane, bs = mslot;
#pragma unroll
        for (int off = 32; off >= 1; off >>= 1) {
            const float ov = __shfl_xor(bv, off);
            const int ol = __shfl_xor(bl, off);
            const int os = __shfl_xor(bs, off);
            if (ov > bv || (ov == bv && ol < bl)) { bv = ov; bl = ol; bs = os; }
        }
        sum += bv;
        if (lane == bl) v[bs] = -1e30f;
    }
    if (lane == 0) out[b] = sum * (1.f / 17.f);
}

// ---------------------------------------------------------------------------
// Orchestration.
//   (hh,hl) <- gemm1(f_f, Wf)            [AMODE2, planes out]
//   xbuf    <- gemm2(hh,hl, W1)          [AMODE1]
//   sbuf    <- scan(xbuf)
//   xbuf    <- gemm3(sbuf, W2)           [AMODE0]
//   sbuf    <- scan(xbuf)
//   (zh,zl)=(hh,hl) <- gemm4(sbuf, Mw1)  [AMODE0, relu, planes out; h dead]
//   logits  <- mil2_dp(zh,zl)            out <- topk
// ---------------------------------------------------------------------------
extern "C" void kernel_launch(void* const* d_in, const int* in_sizes, int n_in,
                              void* d_out, int out_size, void* d_ws, size_t ws_size,
                              hipStream_t stream) {
    const float* f_f = (const float*)d_in[0];
    const float* Wf  = (const float*)d_in[2];
    const float* bf  = (const float*)d_in[3];
    const float* W1  = (const float*)d_in[4];
    const float* b1  = (const float*)d_in[5];
    const float* W2  = (const float*)d_in[6];
    const float* b2  = (const float*)d_in[7];
    const float* Mw1 = (const float*)d_in[8];
    const float* Mb1 = (const float*)d_in[9];
    const float* Mw2 = (const float*)d_in[10];
    const float* Mb2 = (const float*)d_in[11];
    const float* Mw3 = (const float*)d_in[12];
    const float* Mb3 = (const float*)d_in[13];
    float* out = (float*)d_out;

    char* ws = (char*)d_ws;
    const size_t NE = (size_t)M_ * H_;  // 8388608 elems per activation
    ushort_t* hh = (ushort_t*)ws;                        // 16.8 MB
    ushort_t* hl = hh + NE;                              // 16.8 MB
    float* xbuf = (float*)(hl + NE);                     // 33.5 MB
    ushort_t* sbuf = (ushort_t*)(xbuf + NE);             // 16.8 MB
    ushort_t* wfh = sbuf + NE;
    ushort_t* wfl = wfh + 524288;
    ushort_t* w1h = wfl + 524288;
    ushort_t* w1l = w1h + 262144;
    ushort_t* w2h = w1l + 262144;
    ushort_t* w2l = w2h + 262144;
    ushort_t* m1h = w2l + 262144;
    ushort_t* m1l = m1h + 262144;
    ushort_t* m2h = m1l + 262144;
    ushort_t* m2l = m2h + 16384;
    float* logits = (float*)(m2l + 16384 + 128);
    ushort_t* zh = hh;  // overlay: h planes dead after gemm2
    ushort_t* zl = hl;

    const dim3 blk(256);
    const dim3 gg(4, 128);  // 512 wg

    split_w<<<dim3(524288 / 1024), blk, 0, stream>>>(Wf, wfh, wfl);
    split_w<<<dim3(262144 / 1024), blk, 0, stream>>>(W1, w1h, w1l);
    split_w<<<dim3(262144 / 1024), blk, 0, stream>>>(W2, w2h, w2l);
    split_w<<<dim3(262144 / 1024), blk, 0, stream>>>(Mw1, m1h, m1l);
    split_w<<<dim3(16384 / 1024), blk, 0, stream>>>(Mw2, m2h, m2l);

    gemm_dp<2, 0, 1><<<gg, blk, 0, stream>>>(f_f, nullptr, nullptr, wfh, wfl,
                                             bf, nullptr, hh, hl, M_, H_, F_);
    gemm_dp<1, 0, 0><<<gg, blk, 0, stream>>>(nullptr, hh, hl, w1h, w1l, b1,
                                             xbuf, nullptr, nullptr, M_, H_, H_);
    leaky_scan<<<dim3((B_ * H_) / 256), blk, 0, stream>>>(xbuf, sbuf);
    gemm_dp<0, 0, 0><<<gg, blk, 0, stream>>>(nullptr, sbuf, nullptr, w2h, w2l,
                                             b2, xbuf, nullptr, nullptr, M_, H_, H_);
    leaky_scan<<<dim3((B_ * H_) / 256), blk, 0, stream>>>(xbuf, sbuf);
    gemm_dp<0, 1, 1><<<gg, blk, 0, stream>>>(nullptr, sbuf, nullptr, m1h, m1l,
                                             Mb1, nullptr, zh, zl, M_, H_, H_);
    mil2_dp<<<dim3(M_ / 128), blk, 0, stream>>>(zh, zl, m2h, m2l, Mb2, Mw3,
                                                Mb3, logits);
    topk_mean<<<dim3(B_), dim3(64), 0, stream>>>(logits, out);
}